// Round 4
// baseline (13.544 us; speedup 1.0000x reference)
//
#include <hip/hip_runtime.h>

// MPSELoss one-dispatch, 8 blocks x 1024 threads (4 rows per block):
// loss = sum_b [ N*sum_i d_bi^2 - (sum_i d_bi)^2 ] / (B * N*(N-1)/2),  d = outputs - targets
// Each 256-thread group reduces one row; group leaders release-store per-row double
// partials; one counter bump per block (8 total). Winner = (prev & 7) == 7, which fires
// exactly once per call for ANY initial counter value (poison-proof, no init needed).
// Winner acquire-loads the 32 partials in fixed order -> bit-deterministic scalar.

#define BB 32
#define NN 2048
#define NBLK 8
#define ROWS_PER_BLK (BB / NBLK)   // 4

__global__ void __launch_bounds__(1024) mpse_onepass8(const float* __restrict__ outs,
                                                      const float* __restrict__ tgts,
                                                      double* __restrict__ partials,
                                                      unsigned int* __restrict__ counter,
                                                      float* __restrict__ out) {
    const int t = threadIdx.x;
    const int g = t >> 8;                       // row-group 0..3 within block
    const int idx = t & 255;                    // thread within group
    const int row = blockIdx.x * ROWS_PER_BLK + g;

    const float4* o4 = reinterpret_cast<const float4*>(outs + (size_t)row * NN);
    const float4* g4 = reinterpret_cast<const float4*>(tgts + (size_t)row * NN);

    float s1 = 0.f, s2 = 0.f;
    // 512 float4 per row; 256 threads/group -> 2 float4 each, coalesced.
#pragma unroll
    for (int k = 0; k < 2; ++k) {
        float4 a = o4[idx + k * 256];
        float4 b = g4[idx + k * 256];
        float d0 = a.x - b.x;
        float d1 = a.y - b.y;
        float d2 = a.z - b.z;
        float d3 = a.w - b.w;
        s1 += (d0 + d1) + (d2 + d3);
        s2 += (d0 * d0 + d1 * d1) + (d2 * d2 + d3 * d3);
    }

    // wave64 butterfly
#pragma unroll
    for (int off = 32; off >= 1; off >>= 1) {
        s1 += __shfl_xor(s1, off);
        s2 += __shfl_xor(s2, off);
    }

    // 4 groups x 4 waves of per-wave partials
    __shared__ float sh1[ROWS_PER_BLK][4];
    __shared__ float sh2[ROWS_PER_BLK][4];
    const int wave = idx >> 6;                  // wave within group (0..3)
    if ((idx & 63) == 0) {
        sh1[g][wave] = s1;
        sh2[g][wave] = s2;
    }
    __syncthreads();

    if (idx == 0) {  // 4 group leaders per block
        float S1 = (sh1[g][0] + sh1[g][1]) + (sh1[g][2] + sh1[g][3]);
        float S2 = (sh2[g][0] + sh2[g][1]) + (sh2[g][2] + sh2[g][3]);
        double val = (double)NN * (double)S2 - (double)S1 * (double)S1;
        __hip_atomic_store(&partials[row], val, __ATOMIC_RELEASE, __HIP_MEMORY_SCOPE_AGENT);
    }
    __syncthreads();   // drains vmcnt: all 4 partial stores have left the CU

    if (t == 0) {
        __threadfence();  // publish group leaders' stores at agent scope
        unsigned int prev = __hip_atomic_fetch_add(counter, 1u, __ATOMIC_ACQ_REL,
                                                   __HIP_MEMORY_SCOPE_AGENT);
        if ((prev & (NBLK - 1)) == (NBLK - 1)) {
            double acc = 0.0;
#pragma unroll
            for (int r = 0; r < BB; ++r) {
                acc += __hip_atomic_load(&partials[r], __ATOMIC_ACQUIRE,
                                         __HIP_MEMORY_SCOPE_AGENT);
            }
            const double count = (double)BB * ((double)NN * (double)(NN - 1) * 0.5);
            out[0] = (float)(acc / count);
        }
    }
}

extern "C" void kernel_launch(void* const* d_in, const int* in_sizes, int n_in,
                              void* d_out, int out_size, void* d_ws, size_t ws_size,
                              hipStream_t stream) {
    const float* outs = (const float*)d_in[0];
    const float* tgts = (const float*)d_in[1];
    float* out = (float*)d_out;                       // 1 float
    double* partials = (double*)d_ws;                 // 32 doubles
    unsigned int* counter = (unsigned int*)((char*)d_ws + BB * sizeof(double));

    mpse_onepass8<<<dim3(NBLK), dim3(1024), 0, stream>>>(outs, tgts, partials, counter, out);
}

// Round 5
// 11.725 us; speedup vs baseline: 1.1551x; 1.1551x over previous
//
#include <hip/hip_runtime.h>

// MPSELoss one-dispatch, 4 blocks x 1024 threads (8 rows per block):
// loss = sum_b [ N*sum_i d_bi^2 - (sum_i d_bi)^2 ] / (B * N*(N-1)/2),  d = outputs - targets
//
// Cross-block combine redesigned vs R3/R4: each block folds to ONE double, plain-stores
// it to slot[bid], then does a single fetch_add(ACQ_REL, AGENT). The last-arriving
// block's RMW synchronizes-with all earlier release-RMWs (release sequence), making the
// plain slot stores visible -> winner uses PLAIN loads (no per-element acquire, no
// threadfence). Winner test (prev & 3) == 3 fires exactly once per call for any initial
// counter value (poison-proof). Fixed-order sums -> bit-deterministic.

#define BB 32
#define NN 2048
#define NBLK 4
#define ROWS_PER_BLK (BB / NBLK)   // 8 rows, 128 threads per row

__global__ void __launch_bounds__(1024) mpse_onepass4(const float* __restrict__ outs,
                                                      const float* __restrict__ tgts,
                                                      double* __restrict__ slots,
                                                      unsigned int* __restrict__ counter,
                                                      float* __restrict__ out) {
    const int t = threadIdx.x;
    const int g = t >> 7;                 // row-group 0..7 within block
    const int idx = t & 127;              // thread within row-group
    const int row = blockIdx.x * ROWS_PER_BLK + g;

    const float4* o4 = reinterpret_cast<const float4*>(outs + (size_t)row * NN);
    const float4* g4 = reinterpret_cast<const float4*>(tgts + (size_t)row * NN);

    float s1 = 0.f, s2 = 0.f;
    // 512 float4 per row; 128 threads/row -> 4 float4 each per tensor, coalesced.
#pragma unroll
    for (int j = 0; j < 4; ++j) {
        float4 a = o4[idx + j * 128];
        float4 b = g4[idx + j * 128];
        float d0 = a.x - b.x;
        float d1 = a.y - b.y;
        float d2 = a.z - b.z;
        float d3 = a.w - b.w;
        s1 += (d0 + d1) + (d2 + d3);
        s2 += (d0 * d0 + d1 * d1) + (d2 * d2 + d3 * d3);
    }

    // full-wave butterfly (each row spans exactly 2 whole waves)
#pragma unroll
    for (int off = 32; off >= 1; off >>= 1) {
        s1 += __shfl_xor(s1, off);
        s2 += __shfl_xor(s2, off);
    }

    __shared__ float sh1[ROWS_PER_BLK][2];
    __shared__ float sh2[ROWS_PER_BLK][2];
    __shared__ double dval[ROWS_PER_BLK];
    const int wv = (t >> 6) & 1;          // which of the row's 2 waves
    if ((t & 63) == 0) {
        sh1[g][wv] = s1;
        sh2[g][wv] = s2;
    }
    __syncthreads();

    if (idx == 0) {                       // 8 row leaders
        float S1 = sh1[g][0] + sh1[g][1];
        float S2 = sh2[g][0] + sh2[g][1];
        dval[g] = (double)NN * (double)S2 - (double)S1 * (double)S1;
    }
    __syncthreads();

    if (t == 0) {
        double acc = 0.0;
#pragma unroll
        for (int r = 0; r < ROWS_PER_BLK; ++r) acc += dval[r];  // fixed order
        slots[blockIdx.x] = acc;          // plain store; published by the release-RMW below

        unsigned int prev = __hip_atomic_fetch_add(counter, 1u, __ATOMIC_ACQ_REL,
                                                   __HIP_MEMORY_SCOPE_AGENT);
        if ((prev & (NBLK - 1)) == (NBLK - 1)) {
            // last arrival: synchronizes-with the other blocks' release-RMWs,
            // so their plain slot stores are visible to plain loads here.
            double total = 0.0;
#pragma unroll
            for (int r = 0; r < NBLK; ++r) total += slots[r];   // fixed order
            const double count = (double)BB * ((double)NN * (double)(NN - 1) * 0.5);
            out[0] = (float)(total / count);
        }
    }
}

extern "C" void kernel_launch(void* const* d_in, const int* in_sizes, int n_in,
                              void* d_out, int out_size, void* d_ws, size_t ws_size,
                              hipStream_t stream) {
    const float* outs = (const float*)d_in[0];
    const float* tgts = (const float*)d_in[1];
    float* out = (float*)d_out;                       // 1 float
    double* slots = (double*)d_ws;                    // 4 doubles
    unsigned int* counter = (unsigned int*)((char*)d_ws + NBLK * sizeof(double));

    mpse_onepass4<<<dim3(NBLK), dim3(1024), 0, stream>>>(outs, tgts, slots, counter, out);
}

// Round 6
// 9.599 us; speedup vs baseline: 1.4110x; 1.2215x over previous
//
#include <hip/hip_runtime.h>

// MPSELoss one-dispatch, 8 blocks x 1024 threads (4 rows per block).
// loss = sum_b [ N*sum_i d_bi^2 - (sum_i d_bi)^2 ] / (B * N*(N-1)/2),  d = outputs - targets
//
// Cross-block combine with ZERO cache-maintenance: all cross-block traffic uses
// agent-scope RELAXED atomics (LLC-direct, no buffer_wbl2/buffer_inv emitted — unlike
// acquire/release which cost µs of L2 writeback/invalidate per XCD, the R3-R5 lesson).
// Ordering comes from hardware: leader stores its slot (relaxed atomic), drains vmcnt
// (store ack'd at the coherence point), THEN bumps the counter (relaxed RMW). The winner
// ((prev & 7) == 7 — fires exactly once per call for ANY initial counter value, so the
// 0xAA poison is harmless) relaxed-loads all 8 slots: every slot store provably reached
// LLC before its owner's RMW. Fixed-order summation -> bit-deterministic.

#define BB 32
#define NN 2048
#define NBLK 8
#define RPB (BB / NBLK)   // 4 rows per block, 256 threads per row

__global__ void __launch_bounds__(1024) mpse_relaxed8(const float* __restrict__ outs,
                                                      const float* __restrict__ tgts,
                                                      double* __restrict__ slots,
                                                      unsigned int* __restrict__ counter,
                                                      float* __restrict__ out) {
    const int t = threadIdx.x;
    const int g = t >> 8;                 // row-group 0..3 within block
    const int idx = t & 255;              // thread within row-group
    const int row = blockIdx.x * RPB + g;

    const float4* o4 = reinterpret_cast<const float4*>(outs + (size_t)row * NN);
    const float4* g4 = reinterpret_cast<const float4*>(tgts + (size_t)row * NN);

    float s1 = 0.f, s2 = 0.f;
    // 512 float4 per row; 256 threads/row -> 2 float4 each per tensor, coalesced 4KB segs.
#pragma unroll
    for (int k = 0; k < 2; ++k) {
        float4 a = o4[idx + k * 256];
        float4 b = g4[idx + k * 256];
        float d0 = a.x - b.x;
        float d1 = a.y - b.y;
        float d2 = a.z - b.z;
        float d3 = a.w - b.w;
        s1 += (d0 + d1) + (d2 + d3);
        s2 += (d0 * d0 + d1 * d1) + (d2 * d2 + d3 * d3);
    }

    // wave64 butterfly
#pragma unroll
    for (int off = 32; off >= 1; off >>= 1) {
        s1 += __shfl_xor(s1, off);
        s2 += __shfl_xor(s2, off);
    }

    // 16 waves; row g owns waves 4g..4g+3
    __shared__ float sh1[16];
    __shared__ float sh2[16];
    const int wave = t >> 6;
    if ((t & 63) == 0) {
        sh1[wave] = s1;
        sh2[wave] = s2;
    }
    __syncthreads();

    if (t < 64) {                          // wave 0 finishes the block
        double v = 0.0;
        if (t < RPB) {                     // thread t assembles row t of this block
            float S1 = (sh1[4 * t] + sh1[4 * t + 1]) + (sh1[4 * t + 2] + sh1[4 * t + 3]);
            float S2 = (sh2[4 * t] + sh2[4 * t + 1]) + (sh2[4 * t + 2] + sh2[4 * t + 3]);
            v = (double)NN * (double)S2 - (double)S1 * (double)S1;
        }
        // combine the 4 row values within wave 0, fixed order
        double a0 = __shfl(v, 0);
        double a1 = __shfl(v, 1);
        double a2 = __shfl(v, 2);
        double a3 = __shfl(v, 3);
        if (t == 0) {
            double acc = (a0 + a1) + (a2 + a3);
            __hip_atomic_store(&slots[blockIdx.x], acc, __ATOMIC_RELAXED,
                               __HIP_MEMORY_SCOPE_AGENT);
            // drain: our slot store is ack'd at the coherence point before the RMW issues
            asm volatile("s_waitcnt vmcnt(0)" ::: "memory");
            unsigned int prev = __hip_atomic_fetch_add(counter, 1u, __ATOMIC_RELAXED,
                                                       __HIP_MEMORY_SCOPE_AGENT);
            asm volatile("" ::: "memory");  // keep slot loads below the RMW
            if ((prev & (NBLK - 1)) == (NBLK - 1)) {
                double total = 0.0;
#pragma unroll
                for (int r = 0; r < NBLK; ++r) {
                    total += __hip_atomic_load(&slots[r], __ATOMIC_RELAXED,
                                               __HIP_MEMORY_SCOPE_AGENT);
                }
                const double count = (double)BB * ((double)NN * (double)(NN - 1) * 0.5);
                out[0] = (float)(total / count);
            }
        }
    }
}

extern "C" void kernel_launch(void* const* d_in, const int* in_sizes, int n_in,
                              void* d_out, int out_size, void* d_ws, size_t ws_size,
                              hipStream_t stream) {
    const float* outs = (const float*)d_in[0];
    const float* tgts = (const float*)d_in[1];
    float* out = (float*)d_out;                       // 1 float
    double* slots = (double*)d_ws;                    // 8 doubles
    unsigned int* counter = (unsigned int*)((char*)d_ws + NBLK * sizeof(double));

    mpse_relaxed8<<<dim3(NBLK), dim3(1024), 0, stream>>>(outs, tgts, slots, counter, out);
}